// Round 2
// baseline (1099.689 us; speedup 1.0000x reference)
//
#include <hip/hip_runtime.h>

typedef unsigned short UST;
typedef __attribute__((ext_vector_type(8))) short short8;
typedef __attribute__((ext_vector_type(4))) float f32x4;
typedef __attribute__((ext_vector_type(4))) unsigned short us4;

#define DEV __device__ __forceinline__

DEV float b2f(UST u){ union{unsigned int i; float f;} x; x.i=((unsigned int)u)<<16; return x.f; }
DEV UST f2b(float f){ union{float f; unsigned int i;} x; x.f=f; return (UST)((x.i + 0x7FFFu + ((x.i>>16)&1u))>>16); }
// flag: 1 = inputs are bf16, 0 = inputs are f32
DEV float ldf(const void* p, size_t i, int fl){ return fl ? b2f(((const UST*)p)[i]) : ((const float*)p)[i]; }

DEV void g2l16(const UST* g, UST* l){
  __builtin_amdgcn_global_load_lds((const __attribute__((address_space(1))) unsigned int*)g,
                                   (__attribute__((address_space(3))) unsigned int*)l, 16, 0, 0);
}

// ---------------- dtype detection ----------------
// f32 data read as u32: bits 7..14 are mantissa bits (uniform). bf16-pair: bits 7..14
// are the LOW bf16 element's exponent field, concentrated in [100,140] for N(0,sigma) data.
__global__ __launch_bounds__(256) void detect_k(const unsigned int* __restrict__ x, int* __restrict__ flag)
{
  int tid = threadIdx.x;
  int cnt = 0;
#pragma unroll
  for (int j=0;j<4;j++){
    unsigned e = (x[tid*4+j] >> 7) & 0xFF;
    cnt += (e >= 100 && e <= 140) ? 1 : 0;
  }
  __shared__ int tot;
  if (tid==0) tot = 0;
  __syncthreads();
  atomicAdd(&tot, cnt);
  __syncthreads();
  if (tid==0) flag[0] = (tot > 512) ? 1 : 0;
}

// ---------------- GEMM: C[M,N] = A[M,K] @ Bt[N,K]^T + bias ----------------
// EPI: 0 store bf16; 1 gelu->bf16; 2 relu->bf16; 3 resid+=; 4 resid+= & aux=bf16(resid); 5 out=resid+acc (dtype per flag)
template<int EPI, bool MTAIL>
__global__ __launch_bounds__(256) void gemm128(
    const UST* __restrict__ A, const UST* __restrict__ Bt, const void* __restrict__ bias,
    int M, int N, int K,
    UST* __restrict__ out, float* __restrict__ resid, void* __restrict__ aux,
    const int* __restrict__ flag)
{
  __shared__ UST As[128*32];
  __shared__ UST Bs[128*32];
  const int fl = flag[0];
  int tid = threadIdx.x;
  int bx = blockIdx.x, by = blockIdx.y;
  int lane = tid & 63, w = tid >> 6;
  int wr = w >> 1, wc = w & 1;
  int lr = lane & 15, lk = (lane >> 4) << 3;

  int c0 = tid, c1 = tid + 256;
  int ar0 = by*128 + (c0>>2), ar1 = by*128 + (c1>>2);
  if (MTAIL){ ar0 = ar0 < M ? ar0 : M-1; ar1 = ar1 < M ? ar1 : M-1; }
  int br0 = bx*128 + (c0>>2), br1 = bx*128 + (c1>>2);
  int ak0 = (c0&3)<<3, ak1 = (c1&3)<<3;
  const UST* pa0 = A + (size_t)ar0*K + ak0;
  const UST* pa1 = A + (size_t)ar1*K + ak1;
  const UST* pb0 = Bt + (size_t)br0*K + ak0;
  const UST* pb1 = Bt + (size_t)br1*K + ak1;
  UST* la0 = &As[c0*8]; UST* la1 = &As[c1*8];
  UST* lb0 = &Bs[c0*8]; UST* lb1 = &Bs[c1*8];

  f32x4 acc[4][4] = {};

  for (int k0 = 0; k0 < K; k0 += 32){
    g2l16(pa0, la0); g2l16(pa1, la1);
    g2l16(pb0, lb0); g2l16(pb1, lb1);
    pa0 += 32; pa1 += 32; pb0 += 32; pb1 += 32;
    __syncthreads();
    short8 af[4], bf[4];
#pragma unroll
    for (int m=0;m<4;m++) af[m] = *(const short8*)&As[(wr*64 + m*16 + lr)*32 + lk];
#pragma unroll
    for (int n=0;n<4;n++) bf[n] = *(const short8*)&Bs[(wc*64 + n*16 + lr)*32 + lk];
#pragma unroll
    for (int m=0;m<4;m++)
#pragma unroll
      for (int n=0;n<4;n++)
        acc[m][n] = __builtin_amdgcn_mfma_f32_16x16x32_bf16(af[m], bf[n], acc[m][n], 0,0,0);
    __syncthreads();
  }

  float bv[4];
#pragma unroll
  for (int n=0;n<4;n++) bv[n] = ldf(bias, bx*128 + wc*64 + n*16 + lr, fl);
#pragma unroll
  for (int m=0;m<4;m++){
#pragma unroll
    for (int r=0;r<4;r++){
      int gr = by*128 + wr*64 + m*16 + ((lane>>4)<<2) + r;
      if (MTAIL && gr >= M) continue;
#pragma unroll
      for (int n=0;n<4;n++){
        int gc = bx*128 + wc*64 + n*16 + lr;
        float v = acc[m][n][r] + bv[n];
        size_t idx = (size_t)gr*N + gc;
        if (EPI == 0){ out[idx] = f2b(v); }
        else if (EPI == 1){ float e = __expf(-1.5957691216f*(v + 0.044715f*v*v*v)); out[idx] = f2b(v/(1.f+e)); }
        else if (EPI == 2){ out[idx] = f2b(v > 0.f ? v : 0.f); }
        else if (EPI == 3){ resid[idx] += v; }
        else if (EPI == 4){ float x2 = resid[idx] + v; resid[idx] = x2; ((UST*)aux)[idx] = f2b(x2); }
        else { float x2 = resid[idx] + v; if (fl) ((UST*)aux)[idx] = f2b(x2); else ((float*)aux)[idx] = x2; }
      }
    }
  }
}

// ---------------- LayerNorm: f32 row -> bf16 ----------------
__global__ __launch_bounds__(256) void ln_k(const float* __restrict__ xf, const void* __restrict__ g,
                                            const void* __restrict__ b, UST* __restrict__ out,
                                            const int* __restrict__ flag)
{
  const int fl = flag[0];
  int row = blockIdx.x, tid = threadIdx.x;
  const float* xr = xf + (size_t)row*1024;
  f32x4 v = *(const f32x4*)&xr[tid*4];
  float s = v[0]+v[1]+v[2]+v[3];
  float ss = v[0]*v[0]+v[1]*v[1]+v[2]*v[2]+v[3]*v[3];
#pragma unroll
  for (int off=32; off>0; off>>=1){ s += __shfl_down(s, off); ss += __shfl_down(ss, off); }
  __shared__ float sm[8];
  int w = tid>>6;
  if ((tid&63)==0){ sm[w] = s; sm[4+w] = ss; }
  __syncthreads();
  s = sm[0]+sm[1]+sm[2]+sm[3];
  ss = sm[4]+sm[5]+sm[6]+sm[7];
  float mu = s*(1.f/1024.f);
  float rs = rsqrtf(ss*(1.f/1024.f) - mu*mu + 1e-5f);
  us4 o;
#pragma unroll
  for (int j=0;j<4;j++){
    int c = tid*4+j;
    o[j] = f2b((v[j]-mu)*rs*ldf(g,c,fl) + ldf(b,c,fl));
  }
  *(us4*)&out[(size_t)row*1024 + tid*4] = o;
}

// ---------------- flash attention (16 q rows per wave) ----------------
#define NEGBIG (-1e30f)
template<bool CAUSAL>
__global__ __launch_bounds__(256) void attn_k(
    const UST* __restrict__ Qb, size_t qB, int qT,
    const UST* __restrict__ Kb, size_t kB, int kT,
    const UST* __restrict__ Vt, int vS,
    UST* __restrict__ O, int nk)
{
  int qblk = blockIdx.x, bh = blockIdx.y;
  int b = bh >> 4, h = bh & 15;
  int tid = threadIdx.x, w = tid >> 6, lane = tid & 63;
  int lr = lane & 15, lk = (lane >> 4) << 3;
  int t0 = qblk*64 + w*16;
  const UST* q = Qb + (size_t)b*qB + h*64;
  const UST* kp = Kb + (size_t)b*kB + h*64;
  const UST* vp = Vt + (size_t)bh*64*vS;
  short8 qf0 = *(const short8*)&q[(size_t)(t0+lr)*qT + lk];
  short8 qf1 = *(const short8*)&q[(size_t)(t0+lr)*qT + 32 + lk];
  f32x4 oacc[4] = {};
  float m[4], l[4];
#pragma unroll
  for (int r=0;r<4;r++){ m[r] = NEGBIG; l[r] = 0.f; }
  __shared__ UST plds[4][16][32];
  int nt = CAUSAL ? ((t0+15)>>5)+1 : ((nk+31)>>5);
  int qr0 = t0 + ((lane>>4)<<2);
  for (int kt=0; kt<nt; kt++){
    int s0 = kt*32;
    f32x4 sf[2] = {};
#pragma unroll
    for (int half=0; half<2; half++){
      const UST* kr = &kp[(size_t)(s0 + half*16 + lr)*kT + lk];
      short8 k0 = *(const short8*)kr;
      short8 k1 = *(const short8*)(kr + 32);
      sf[half] = __builtin_amdgcn_mfma_f32_16x16x32_bf16(qf0, k0, sf[half], 0,0,0);
      sf[half] = __builtin_amdgcn_mfma_f32_16x16x32_bf16(qf1, k1, sf[half], 0,0,0);
    }
    bool needMask = (CAUSAL && (s0+31 > t0)) || (s0+31 >= nk);
#pragma unroll
    for (int half=0; half<2; half++)
#pragma unroll
      for (int r=0;r<4;r++){
        float sv = sf[half][r]*0.125f;
        if (needMask){
          int key = s0 + half*16 + lr;
          if ((CAUSAL && key > qr0 + r) || key >= nk) sv = NEGBIG;
        }
        sf[half][r] = sv;
      }
    float mx[4];
#pragma unroll
    for (int r=0;r<4;r++) mx[r] = fmaxf(sf[0][r], sf[1][r]);
#pragma unroll
    for (int off=1; off<16; off<<=1)
#pragma unroll
      for (int r=0;r<4;r++) mx[r] = fmaxf(mx[r], __shfl_xor(mx[r], off));
    float scl[4];
#pragma unroll
    for (int r=0;r<4;r++){
      float mn = fmaxf(m[r], mx[r]);
      scl[r] = __expf(m[r] - mn);
      m[r] = mn;
    }
#pragma unroll
    for (int half=0; half<2; half++)
#pragma unroll
      for (int r=0;r<4;r++){
        float d = sf[half][r] - m[r];
        sf[half][r] = (d < -80.f) ? 0.f : __expf(d);
      }
    float sum[4];
#pragma unroll
    for (int r=0;r<4;r++) sum[r] = sf[0][r] + sf[1][r];
#pragma unroll
    for (int off=1; off<16; off<<=1)
#pragma unroll
      for (int r=0;r<4;r++) sum[r] += __shfl_xor(sum[r], off);
#pragma unroll
    for (int r=0;r<4;r++) l[r] = l[r]*scl[r] + sum[r];
#pragma unroll
    for (int nf=0;nf<4;nf++)
#pragma unroll
      for (int r=0;r<4;r++) oacc[nf][r] *= scl[r];
#pragma unroll
    for (int half=0; half<2; half++)
#pragma unroll
      for (int r=0;r<4;r++)
        plds[w][((lane>>4)<<2)+r][half*16+lr] = f2b(sf[half][r]);
    short8 pf = *(const short8*)&plds[w][lr][lk];
#pragma unroll
    for (int nf=0;nf<4;nf++){
      short8 vf = *(const short8*)&vp[(size_t)(nf*16+lr)*vS + s0 + lk];
      oacc[nf] = __builtin_amdgcn_mfma_f32_16x16x32_bf16(pf, vf, oacc[nf], 0,0,0);
    }
  }
#pragma unroll
  for (int nf=0;nf<4;nf++)
#pragma unroll
    for (int r=0;r<4;r++){
      int t = t0 + ((lane>>4)<<2) + r;
      O[(size_t)(b*1024 + t)*1024 + h*64 + nf*16 + lr] = f2b(oacc[nf][r] / l[r]);
    }
}

// ---------------- weight transpose: in[K][N] (f32 or bf16) -> out[N][K] bf16 ----------------
__global__ __launch_bounds__(256) void transposeW(const void* __restrict__ in, UST* __restrict__ out,
                                                  int K, int N, const int* __restrict__ flag)
{
  const int fl = flag[0];
  int n0 = blockIdx.x*64, k0 = blockIdx.y*64;
  __shared__ UST t[64][72];
  int tid = threadIdx.x;
  int r = tid>>3, cc = (tid&7)*8;
#pragma unroll
  for (int it=0; it<2; it++){
    int k = r + it*32;
    short8 v;
    if (fl){
      v = *(const short8*)&((const UST*)in)[(size_t)(k0+k)*N + n0 + cc];
    } else {
      const float* inf = (const float*)in;
      f32x4 a = *(const f32x4*)&inf[(size_t)(k0+k)*N + n0 + cc];
      f32x4 b = *(const f32x4*)&inf[(size_t)(k0+k)*N + n0 + cc + 4];
#pragma unroll
      for (int j=0;j<4;j++){ v[j] = (short)f2b(a[j]); v[4+j] = (short)f2b(b[j]); }
    }
    *(short8*)&t[k][cc] = v;
  }
  __syncthreads();
#pragma unroll
  for (int it=0; it<2; it++){
    int n = r + it*32;
    short8 v;
#pragma unroll
    for (int j=0;j<8;j++) v[j] = t[cc+j][n];
    *(short8*)&out[(size_t)(n0+n)*K + k0 + cc] = v;
  }
}

// V (self) from qkv[8192][3072] cols 2048+.. -> vt[bh*64+d][1024]
__global__ __launch_bounds__(256) void transposeVself(const UST* __restrict__ qkv, UST* __restrict__ vt)
{
  int t0 = blockIdx.x*64; int bh = blockIdx.y; int b = bh>>4, h = bh&15;
  __shared__ UST t[64][72];
  int tid = threadIdx.x, r = tid>>3, cc = (tid&7)*8;
#pragma unroll
  for (int it=0; it<2; it++){
    int tt = r + it*32;
    short8 v = *(const short8*)&qkv[((size_t)(b*1024 + t0 + tt))*3072 + 2048 + h*64 + cc];
    *(short8*)&t[tt][cc] = v;
  }
  __syncthreads();
#pragma unroll
  for (int it=0; it<2; it++){
    int d = r + it*32;
    short8 v;
#pragma unroll
    for (int j=0;j<8;j++) v[j] = t[cc+j][d];
    *(short8*)&vt[((size_t)(bh*64 + d))*1024 + t0 + cc] = v;
  }
}

// V (cross) from v2[2056][1024] -> vt2[bh*64+d][288] (s<257 valid)
__global__ __launch_bounds__(256) void transposeVcross(const UST* __restrict__ v2, UST* __restrict__ vt2)
{
  int s0 = blockIdx.x*64; int bh = blockIdx.y; int b = bh>>4, h = bh&15;
  __shared__ UST t[64][72];
  int tid = threadIdx.x, r = tid>>3, cc = (tid&7)*8;
#pragma unroll
  for (int it=0; it<2; it++){
    int s = s0 + r + it*32; if (s > 256) s = 256;
    short8 v = *(const short8*)&v2[((size_t)(b*257 + s))*1024 + h*64 + cc];
    *(short8*)&t[r+it*32][cc] = v;
  }
  __syncthreads();
#pragma unroll
  for (int it=0; it<2; it++){
    int d = r + it*32;
#pragma unroll
    for (int j=0;j<8;j++){
      int s = s0 + cc + j;
      if (s < 257) vt2[((size_t)(bh*64 + d))*288 + s] = t[cc+j][d];
    }
  }
}

// x (f32 or bf16) -> f32 residual stream
__global__ __launch_bounds__(256) void cvt_f32(const void* __restrict__ in, float* __restrict__ out,
                                               const int* __restrict__ flag)
{
  const int fl = flag[0];
  size_t i = ((size_t)blockIdx.x*256 + threadIdx.x)*4;
  f32x4 o;
  if (fl){
    us4 v = *(const us4*)&((const UST*)in)[i];
#pragma unroll
    for (int j=0;j<4;j++) o[j] = b2f(v[j]);
  } else {
    o = *(const f32x4*)&((const float*)in)[i];
  }
  *(f32x4*)&out[i] = o;
}

// enc -> enc_c (bf16) AND passthrough to out (exact, dtype per flag)
__global__ __launch_bounds__(256) void encpass(const void* __restrict__ in, UST* __restrict__ enc_c,
                                               void* __restrict__ outp, const int* __restrict__ flag)
{
  const int fl = flag[0];
  size_t i = ((size_t)blockIdx.x*256 + threadIdx.x)*4;
  if (fl){
    us4 v = *(const us4*)&((const UST*)in)[i];
    *(us4*)&enc_c[i] = v;
    *(us4*)&((UST*)outp)[8388608 + i] = v;
  } else {
    f32x4 v = *(const f32x4*)&((const float*)in)[i];
    us4 c;
#pragma unroll
    for (int j=0;j<4;j++) c[j] = f2b(v[j]);
    *(us4*)&enc_c[i] = c;
    *(f32x4*)&((float*)outp)[8388608 + i] = v;
  }
}

extern "C" void kernel_launch(void* const* d_in, const int* in_sizes, int n_in,
                              void* d_out, int out_size, void* d_ws, size_t ws_size,
                              hipStream_t stream) {
  (void)in_sizes; (void)n_in; (void)out_size; (void)ws_size;
  const void* x       = d_in[0];
  const void* enc     = d_in[1];
  const void* ln1g    = d_in[2];
  const void* ln1b    = d_in[3];
  const void* ln2g    = d_in[4];
  const void* ln2b    = d_in[5];
  const void* ln3g    = d_in[6];
  const void* ln3b    = d_in[7];
  const void* qkvW    = d_in[8];
  const void* qkvB    = d_in[9];
  const void* projW   = d_in[10];
  const void* projB   = d_in[11];
  const void* caqW    = d_in[12];
  const void* caqB    = d_in[13];
  const void* cakW    = d_in[14];
  const void* cakB    = d_in[15];
  const void* cavW    = d_in[16];
  const void* cavB    = d_in[17];
  const void* caprojW = d_in[18];
  const void* caprojB = d_in[19];
  const void* fcW     = d_in[20];
  const void* fcB     = d_in[21];
  const void* mlpW    = d_in[22];
  const void* mlpB    = d_in[23];
  const void* adwW    = d_in[24];
  const void* adwB    = d_in[25];
  const void* aupW    = d_in[26];
  const void* aupB    = d_in[27];

  unsigned char* ws = (unsigned char*)d_ws;
  int*   flag = (int*)ws;                            // 256 B
  float* xf   = (float*)(ws + 256);                  // 33,554,432 B
  UST*   big  = (UST*)(ws + 33554688);               // 67,108,864 B
  UST*   h    = (UST*)(ws + 100663552);              // 16,777,216 B
  UST*   o    = (UST*)(ws + 117440768);              // 16,777,216 B
  UST*   wT   = (UST*)(ws + 134217984);              // 34,603,008 B
  UST*   encc = (UST*)(ws + 168820992);              //  4,210,688 B  (total ~173 MB)
  UST* qkvT    = wT;
  UST* projT   = wT + 3145728;
  UST* caqT    = wT + 4194304;
  UST* cakT    = wT + 5242880;
  UST* cavT    = wT + 6291456;
  UST* caprojT = wT + 7340032;
  UST* fcT     = wT + 8388608;
  UST* mlpT    = wT + 12582912;
  UST* adwT    = wT + 16777216;
  UST* aupT    = wT + 17039360;
  // inside big:
  UST* q2  = big;                 // 16.8 MB
  UST* k2  = big + 8388608;       //  4.2 MB
  UST* v2  = big + 10493952;      //  4.2 MB
  UST* vtX = big + 25165824;      // 16 MB (V^T scratch; coexists with qkv[0..48MB) / q2k2v2)

  detect_k<<<1,256,0,stream>>>((const unsigned int*)x, flag);

  // --- weight transposes ([K][N] -> [N][K] bf16) ---
  transposeW<<<dim3(48,16),256,0,stream>>>(qkvW,    qkvT,    1024, 3072, flag);
  transposeW<<<dim3(16,16),256,0,stream>>>(projW,   projT,   1024, 1024, flag);
  transposeW<<<dim3(16,16),256,0,stream>>>(caqW,    caqT,    1024, 1024, flag);
  transposeW<<<dim3(16,16),256,0,stream>>>(cakW,    cakT,    1024, 1024, flag);
  transposeW<<<dim3(16,16),256,0,stream>>>(cavW,    cavT,    1024, 1024, flag);
  transposeW<<<dim3(16,16),256,0,stream>>>(caprojW, caprojT, 1024, 1024, flag);
  transposeW<<<dim3(64,16),256,0,stream>>>(fcW,     fcT,     1024, 4096, flag);
  transposeW<<<dim3(16,64),256,0,stream>>>(mlpW,    mlpT,    4096, 1024, flag);
  transposeW<<<dim3(4,16), 256,0,stream>>>(adwW,    adwT,    1024, 256,  flag);
  transposeW<<<dim3(16,4), 256,0,stream>>>(aupW,    aupT,    256,  1024, flag);

  // --- residual stream f32; enc passthrough + bf16 copy ---
  cvt_f32<<<8192,256,0,stream>>>(x, xf, flag);
  encpass<<<2056,256,0,stream>>>(enc, encc, d_out, flag);

  // --- self attention ---
  ln_k<<<8192,256,0,stream>>>(xf, ln1g, ln1b, h, flag);
  gemm128<0,false><<<dim3(24,64),256,0,stream>>>(h, qkvT, qkvB, 8192, 3072, 1024, big, nullptr, nullptr, flag);
  transposeVself<<<dim3(16,128),256,0,stream>>>(big, vtX);
  attn_k<true><<<dim3(16,128),256,0,stream>>>(big, (size_t)1024*3072, 3072,
                                              big+1024, (size_t)1024*3072, 3072,
                                              vtX, 1024, o, 1024);
  gemm128<3,false><<<dim3(8,64),256,0,stream>>>(o, projT, projB, 8192, 1024, 1024, nullptr, xf, nullptr, flag);

  // --- cross attention ---
  ln_k<<<8192,256,0,stream>>>(xf, ln3g, ln3b, h, flag);
  gemm128<0,false><<<dim3(8,64),256,0,stream>>>(h, caqT, caqB, 8192, 1024, 1024, q2, nullptr, nullptr, flag);
  gemm128<0,true ><<<dim3(8,17),256,0,stream>>>(encc, cakT, cakB, 2056, 1024, 1024, k2, nullptr, nullptr, flag);
  gemm128<0,true ><<<dim3(8,17),256,0,stream>>>(encc, cavT, cavB, 2056, 1024, 1024, v2, nullptr, nullptr, flag);
  transposeVcross<<<dim3(5,128),256,0,stream>>>(v2, vtX);
  attn_k<false><<<dim3(16,128),256,0,stream>>>(q2, (size_t)1024*1024, 1024,
                                               k2, (size_t)257*1024, 1024,
                                               vtX, 288, o, 257);
  gemm128<3,false><<<dim3(8,64),256,0,stream>>>(o, caprojT, caprojB, 8192, 1024, 1024, nullptr, xf, nullptr, flag);

  // --- MLP ---
  ln_k<<<8192,256,0,stream>>>(xf, ln2g, ln2b, h, flag);
  gemm128<1,false><<<dim3(32,64),256,0,stream>>>(h, fcT, fcB, 8192, 4096, 1024, big, nullptr, nullptr, flag);
  gemm128<4,false><<<dim3(8,64),256,0,stream>>>(big, mlpT, mlpB, 8192, 1024, 4096, nullptr, xf, h, flag);

  // --- adapter ---
  gemm128<2,false><<<dim3(2,64),256,0,stream>>>(h, adwT, adwB, 8192, 256, 1024, o, nullptr, nullptr, flag);
  gemm128<5,false><<<dim3(8,64),256,0,stream>>>(o, aupT, aupB, 8192, 1024, 256, nullptr, xf, d_out, flag);
}

// Round 4
// 930.362 us; speedup vs baseline: 1.1820x; 1.1820x over previous
//
#include <hip/hip_runtime.h>

typedef unsigned short UST;
typedef __attribute__((ext_vector_type(8))) short short8;
typedef __attribute__((ext_vector_type(4))) float f32x4;
typedef __attribute__((ext_vector_type(4))) unsigned short us4;

#define DEV __device__ __forceinline__

DEV float b2f(UST u){ union{unsigned int i; float f;} x; x.i=((unsigned int)u)<<16; return x.f; }
DEV UST f2b(float f){ union{float f; unsigned int i;} x; x.f=f; return (UST)((x.i + 0x7FFFu + ((x.i>>16)&1u))>>16); }
// flag: 1 = inputs are bf16, 0 = inputs are f32
DEV float ldf(const void* p, size_t i, int fl){ return fl ? b2f(((const UST*)p)[i]) : ((const float*)p)[i]; }

DEV void g2l16(const UST* g, UST* l){
  __builtin_amdgcn_global_load_lds((const __attribute__((address_space(1))) unsigned int*)g,
                                   (__attribute__((address_space(3))) unsigned int*)l, 16, 0, 0);
}

// ---------------- dtype detection ----------------
__global__ __launch_bounds__(256) void detect_k(const unsigned int* __restrict__ x, int* __restrict__ flag)
{
  int tid = threadIdx.x;
  int cnt = 0;
#pragma unroll
  for (int j=0;j<4;j++){
    unsigned e = (x[tid*4+j] >> 7) & 0xFF;
    cnt += (e >= 100 && e <= 140) ? 1 : 0;
  }
  __shared__ int tot;
  if (tid==0) tot = 0;
  __syncthreads();
  atomicAdd(&tot, cnt);
  __syncthreads();
  if (tid==0) flag[0] = (tot > 512) ? 1 : 0;
}

// ---------------- GEMM: C[M,N] = A[M,K] @ Bt[N,K]^T + bias ----------------
// EPI: 0 store bf16; 1 gelu->bf16; 2 relu->bf16; 3 resid+=; 4 resid+= & aux=bf16(resid); 5 out=resid+acc (dtype per flag)
template<int EPI, bool MTAIL>
__global__ __launch_bounds__(256) void gemm128(
    const UST* __restrict__ A, const UST* __restrict__ Bt, const void* __restrict__ bias,
    int M, int N, int K,
    UST* __restrict__ out, float* __restrict__ resid, void* __restrict__ aux,
    const int* __restrict__ flag)
{
  __shared__ UST As[128*32];
  __shared__ UST Bs[128*32];
  const int fl = flag[0];
  int tid = threadIdx.x;
  int bx = blockIdx.x, by = blockIdx.y;
  int lane = tid & 63, w = tid >> 6;
  int wr = w >> 1, wc = w & 1;
  int lr = lane & 15, lk = (lane >> 4) << 3;

  int c0 = tid, c1 = tid + 256;
  int ar0 = by*128 + (c0>>2), ar1 = by*128 + (c1>>2);
  if (MTAIL){ ar0 = ar0 < M ? ar0 : M-1; ar1 = ar1 < M ? ar1 : M-1; }
  int br0 = bx*128 + (c0>>2), br1 = bx*128 + (c1>>2);
  int ak0 = (c0&3)<<3, ak1 = (c1&3)<<3;
  const UST* pa0 = A + (size_t)ar0*K + ak0;
  const UST* pa1 = A + (size_t)ar1*K + ak1;
  const UST* pb0 = Bt + (size_t)br0*K + ak0;
  const UST* pb1 = Bt + (size_t)br1*K + ak1;
  UST* la0 = &As[c0*8]; UST* la1 = &As[c1*8];
  UST* lb0 = &Bs[c0*8]; UST* lb1 = &Bs[c1*8];

  f32x4 acc[4][4] = {};

  for (int k0 = 0; k0 < K; k0 += 32){
    g2l16(pa0, la0); g2l16(pa1, la1);
    g2l16(pb0, lb0); g2l16(pb1, lb1);
    pa0 += 32; pa1 += 32; pb0 += 32; pb1 += 32;
    __syncthreads();
    short8 af[4], bf[4];
#pragma unroll
    for (int m=0;m<4;m++) af[m] = *(const short8*)&As[(wr*64 + m*16 + lr)*32 + lk];
#pragma unroll
    for (int n=0;n<4;n++) bf[n] = *(const short8*)&Bs[(wc*64 + n*16 + lr)*32 + lk];
#pragma unroll
    for (int m=0;m<4;m++)
#pragma unroll
      for (int n=0;n<4;n++)
        acc[m][n] = __builtin_amdgcn_mfma_f32_16x16x32_bf16(af[m], bf[n], acc[m][n], 0,0,0);
    __syncthreads();
  }

  float bv[4];
#pragma unroll
  for (int n=0;n<4;n++) bv[n] = ldf(bias, bx*128 + wc*64 + n*16 + lr, fl);
#pragma unroll
  for (int m=0;m<4;m++){
#pragma unroll
    for (int r=0;r<4;r++){
      int gr = by*128 + wr*64 + m*16 + ((lane>>4)<<2) + r;
      if (MTAIL && gr >= M) continue;
#pragma unroll
      for (int n=0;n<4;n++){
        int gc = bx*128 + wc*64 + n*16 + lr;
        float v = acc[m][n][r] + bv[n];
        size_t idx = (size_t)gr*N + gc;
        if (EPI == 0){ out[idx] = f2b(v); }
        else if (EPI == 1){ float e = __expf(-1.5957691216f*(v + 0.044715f*v*v*v)); out[idx] = f2b(v/(1.f+e)); }
        else if (EPI == 2){ out[idx] = f2b(v > 0.f ? v : 0.f); }
        else if (EPI == 3){ resid[idx] += v; }
        else if (EPI == 4){ float x2 = resid[idx] + v; resid[idx] = x2; ((UST*)aux)[idx] = f2b(x2); }
        else { float x2 = resid[idx] + v; if (fl) ((UST*)aux)[idx] = f2b(x2); else ((float*)aux)[idx] = x2; }
      }
    }
  }
}

// ---------------- LayerNorm: f32 row -> bf16 ----------------
__global__ __launch_bounds__(256) void ln_k(const float* __restrict__ xf, const void* __restrict__ g,
                                            const void* __restrict__ b, UST* __restrict__ out,
                                            const int* __restrict__ flag)
{
  const int fl = flag[0];
  int row = blockIdx.x, tid = threadIdx.x;
  const float* xr = xf + (size_t)row*1024;
  f32x4 v = *(const f32x4*)&xr[tid*4];
  float s = v[0]+v[1]+v[2]+v[3];
  float ss = v[0]*v[0]+v[1]*v[1]+v[2]*v[2]+v[3]*v[3];
#pragma unroll
  for (int off=32; off>0; off>>=1){ s += __shfl_down(s, off); ss += __shfl_down(ss, off); }
  __shared__ float sm[8];
  int w = tid>>6;
  if ((tid&63)==0){ sm[w] = s; sm[4+w] = ss; }
  __syncthreads();
  s = sm[0]+sm[1]+sm[2]+sm[3];
  ss = sm[4]+sm[5]+sm[6]+sm[7];
  float mu = s*(1.f/1024.f);
  float rs = rsqrtf(ss*(1.f/1024.f) - mu*mu + 1e-5f);
  us4 o;
#pragma unroll
  for (int j=0;j<4;j++){
    int c = tid*4+j;
    o[j] = f2b((v[j]-mu)*rs*ldf(g,c,fl) + ldf(b,c,fl));
  }
  *(us4*)&out[(size_t)row*1024 + tid*4] = o;
}

// ---------------- flash attention v2: LDS-staged K/V, KVBLK=64, 2-phase dbuf ----------------
// CAUSAL => paired q-tiles {15-p, p} per block (balanced 17 KV-tiles/block).
#define NEGBIG (-1e30f)
template<bool CAUSAL>
__global__ __launch_bounds__(256) void attn2(
    const UST* __restrict__ Qb, size_t qB, int qT,
    const UST* __restrict__ Kb, size_t kB, int kT,
    const UST* __restrict__ Vt, int vS,
    UST* __restrict__ O, int nk)
{
  __shared__ UST Ks[2][4096];            // [2][64 keys][64 d], XOR-swizzled rows (128B)
  __shared__ UST Vs[2][4096];            // [2][64 d][64 keys], XOR-swizzled rows (128B)
  __shared__ UST plds[4][16][72];        // per-wave P tile, padded rows (144B, 16B-aligned)

  int p = blockIdx.x, bh = blockIdx.y;
  int b = bh >> 4, h = bh & 15;
  int tid = threadIdx.x, w = tid >> 6, lane = tid & 63;
  int lr = lane & 15;
  const UST* q0 = Qb + (size_t)b*qB + h*64;
  const UST* kp = Kb + (size_t)b*kB + h*64;
  const UST* vp = Vt + (size_t)bh*64*vS;
  const int skmax = nk - 1;

  // staging: LDS chunk c holds row (c>>3), source col-bytes ((c&7)*16) ^ ((row&7)<<4)
  auto stageK = [&](int bufi, int s0){
#pragma unroll
    for (int it=0; it<2; it++){
      int c = tid + it*256;
      int s = c >> 3;
      int srcb = ((c & 7) << 4) ^ ((s & 7) << 4);
      int sg = s0 + s; sg = sg <= skmax ? sg : skmax;
      g2l16(kp + (size_t)sg*kT + (srcb>>1), &Ks[bufi][c*8]);
    }
  };
  auto stageV = [&](int bufi, int s0){
#pragma unroll
    for (int it=0; it<2; it++){
      int c = tid + it*256;
      int d = c >> 3;
      int srcb = ((c & 7) << 4) ^ ((d & 7) << 4);
      g2l16(vp + (size_t)d*vS + s0 + (srcb>>1), &Vs[bufi][c*8]);
    }
  };

  int qtiles[2]; int nq;
  if (CAUSAL){ qtiles[0] = 15 - p; qtiles[1] = p; nq = 2; }
  else       { qtiles[0] = p; nq = 1; }

  for (int qi=0; qi<nq; qi++){
    int qt = qtiles[qi];
    int t0 = qt*64 + w*16;
    int qr0 = t0 + ((lane>>4)<<2);
    short8 qf0 = *(const short8*)&q0[(size_t)(t0+lr)*qT + ((lane>>4)<<3)];
    short8 qf1 = *(const short8*)&q0[(size_t)(t0+lr)*qT + 32 + ((lane>>4)<<3)];
    f32x4 oacc[4] = {};
    float m[4], l[4];
#pragma unroll
    for (int r=0;r<4;r++){ m[r] = NEGBIG; l[r] = 0.f; }

    int nt = CAUSAL ? (qt + 1) : ((nk + 63) >> 6);
    int cur = 0;
    stageK(0, 0); stageV(0, 0);
    __syncthreads();

    for (int t=0; t<nt; t++){
      int s0 = t*64;
      int nxt = cur ^ 1;
      if (t+1 < nt){ stageK(nxt, s0 + 64); stageV(nxt, s0 + 64); }

      // ---- QK^T: 64 keys ----
      f32x4 sf[4];
      const char* ksb = (const char*)&Ks[cur][0];
      __builtin_amdgcn_s_setprio(1);
#pragma unroll
      for (int hf=0; hf<4; hf++){
        int r = hf*16 + lr;
        int sw = (r & 7) << 4;
        int lo = (lane >> 4) << 4;
        short8 k0 = *(const short8*)(ksb + r*128 + (lo ^ sw));
        short8 k1 = *(const short8*)(ksb + r*128 + ((64 + lo) ^ sw));
        f32x4 s_ = {};
        s_ = __builtin_amdgcn_mfma_f32_16x16x32_bf16(qf0, k0, s_, 0,0,0);
        s_ = __builtin_amdgcn_mfma_f32_16x16x32_bf16(qf1, k1, s_, 0,0,0);
        sf[hf] = s_;
      }
      __builtin_amdgcn_s_setprio(0);

      bool needMask = (CAUSAL && (s0+63 > t0)) || (s0+63 >= nk);
#pragma unroll
      for (int hf=0; hf<4; hf++)
#pragma unroll
        for (int r=0;r<4;r++){
          float sv = sf[hf][r]*0.125f;
          if (needMask){
            int key = s0 + hf*16 + lr;
            if ((CAUSAL && key > qr0 + r) || key >= nk) sv = NEGBIG;
          }
          sf[hf][r] = sv;
        }

      float mx[4];
#pragma unroll
      for (int r=0;r<4;r++) mx[r] = fmaxf(fmaxf(sf[0][r], sf[1][r]), fmaxf(sf[2][r], sf[3][r]));
#pragma unroll
      for (int off=1; off<16; off<<=1)
#pragma unroll
        for (int r=0;r<4;r++) mx[r] = fmaxf(mx[r], __shfl_xor(mx[r], off));
      float scl[4];
#pragma unroll
      for (int r=0;r<4;r++){
        float mn = fmaxf(m[r], mx[r]);
        scl[r] = __expf(m[r] - mn);
        m[r] = mn;
      }
#pragma unroll
      for (int hf=0; hf<4; hf++)
#pragma unroll
        for (int r=0;r<4;r++){
          float d = sf[hf][r] - m[r];
          sf[hf][r] = (d < -80.f) ? 0.f : __expf(d);
        }
      float sum[4];
#pragma unroll
      for (int r=0;r<4;r++) sum[r] = (sf[0][r] + sf[1][r]) + (sf[2][r] + sf[3][r]);
#pragma unroll
      for (int off=1; off<16; off<<=1)
#pragma unroll
        for (int r=0;r<4;r++) sum[r] += __shfl_xor(sum[r], off);
#pragma unroll
      for (int r=0;r<4;r++) l[r] = l[r]*scl[r] + sum[r];
#pragma unroll
      for (int nf=0;nf<4;nf++)
#pragma unroll
        for (int r=0;r<4;r++) oacc[nf][r] *= scl[r];

      // ---- P -> LDS (per-wave) ----
#pragma unroll
      for (int hf=0; hf<4; hf++)
#pragma unroll
        for (int r=0;r<4;r++)
          plds[w][((lane>>4)<<2)+r][hf*16+lr] = f2b(sf[hf][r]);

      const char* pb = (const char*)&plds[w][0][0];
      short8 pf0 = *(const short8*)(pb + lr*144 +      ((lane>>4)<<4));
      short8 pf1 = *(const short8*)(pb + lr*144 + 64 + ((lane>>4)<<4));

      // ---- PV: oacc += P @ V^T ----
      const char* vsb = (const char*)&Vs[cur][0];
      __builtin_amdgcn_s_setprio(1);
#pragma unroll
      for (int nf=0; nf<4; nf++){
        int d = nf*16 + lr;
        int sw = (d & 7) << 4;
        int lo = (lane >> 4) << 4;
        short8 vf0 = *(const short8*)(vsb + d*128 + (lo ^ sw));
        short8 vf1 = *(const short8*)(vsb + d*128 + ((64 + lo) ^ sw));
        oacc[nf] = __builtin_amdgcn_mfma_f32_16x16x32_bf16(pf0, vf0, oacc[nf], 0,0,0);
        oacc[nf] = __builtin_amdgcn_mfma_f32_16x16x32_bf16(pf1, vf1, oacc[nf], 0,0,0);
      }
      __builtin_amdgcn_s_setprio(0);

      __syncthreads();   // drains next-tile staging (vmcnt) + protects buffers
      cur = nxt;
    }

#pragma unroll
    for (int nf=0;nf<4;nf++)
#pragma unroll
      for (int r=0;r<4;r++){
        int t = t0 + ((lane>>4)<<2) + r;
        O[(size_t)(b*1024 + t)*1024 + h*64 + nf*16 + lr] = f2b(oacc[nf][r] / l[r]);
      }
  }
}

// ---------------- weight transpose: in[K][N] (f32 or bf16) -> out[N][K] bf16 ----------------
__global__ __launch_bounds__(256) void transposeW(const void* __restrict__ in, UST* __restrict__ out,
                                                  int K, int N, const int* __restrict__ flag)
{
  const int fl = flag[0];
  int n0 = blockIdx.x*64, k0 = blockIdx.y*64;
  __shared__ UST t[64][72];
  int tid = threadIdx.x;
  int r = tid>>3, cc = (tid&7)*8;
#pragma unroll
  for (int it=0; it<2; it++){
    int k = r + it*32;
    short8 v;
    if (fl){
      v = *(const short8*)&((const UST*)in)[(size_t)(k0+k)*N + n0 + cc];
    } else {
      const float* inf = (const float*)in;
      f32x4 a = *(const f32x4*)&inf[(size_t)(k0+k)*N + n0 + cc];
      f32x4 b = *(const f32x4*)&inf[(size_t)(k0+k)*N + n0 + cc + 4];
#pragma unroll
      for (int j=0;j<4;j++){ v[j] = (short)f2b(a[j]); v[4+j] = (short)f2b(b[j]); }
    }
    *(short8*)&t[k][cc] = v;
  }
  __syncthreads();
#pragma unroll
  for (int it=0; it<2; it++){
    int n = r + it*32;
    short8 v;
#pragma unroll
    for (int j=0;j<8;j++) v[j] = t[cc+j][n];
    *(short8*)&out[(size_t)(n0+n)*K + k0 + cc] = v;
  }
}

// V (self) from qkv[8192][3072] cols 2048+.. -> vt[bh*64+d][1024]
__global__ __launch_bounds__(256) void transposeVself(const UST* __restrict__ qkv, UST* __restrict__ vt)
{
  int t0 = blockIdx.x*64; int bh = blockIdx.y; int b = bh>>4, h = bh&15;
  __shared__ UST t[64][72];
  int tid = threadIdx.x, r = tid>>3, cc = (tid&7)*8;
#pragma unroll
  for (int it=0; it<2; it++){
    int tt = r + it*32;
    short8 v = *(const short8*)&qkv[((size_t)(b*1024 + t0 + tt))*3072 + 2048 + h*64 + cc];
    *(short8*)&t[tt][cc] = v;
  }
  __syncthreads();
#pragma unroll
  for (int it=0; it<2; it++){
    int d = r + it*32;
    short8 v;
#pragma unroll
    for (int j=0;j<8;j++) v[j] = t[cc+j][d];
    *(short8*)&vt[((size_t)(bh*64 + d))*1024 + t0 + cc] = v;
  }
}

// V (cross) from v2[2056][1024] -> vt2[bh*64+d][288] (s<257 valid)
__global__ __launch_bounds__(256) void transposeVcross(const UST* __restrict__ v2, UST* __restrict__ vt2)
{
  int s0 = blockIdx.x*64; int bh = blockIdx.y; int b = bh>>4, h = bh&15;
  __shared__ UST t[64][72];
  int tid = threadIdx.x, r = tid>>3, cc = (tid&7)*8;
#pragma unroll
  for (int it=0; it<2; it++){
    int s = s0 + r + it*32; if (s > 256) s = 256;
    short8 v = *(const short8*)&v2[((size_t)(b*257 + s))*1024 + h*64 + cc];
    *(short8*)&t[r+it*32][cc] = v;
  }
  __syncthreads();
#pragma unroll
  for (int it=0; it<2; it++){
    int d = r + it*32;
#pragma unroll
    for (int j=0;j<8;j++){
      int s = s0 + cc + j;
      if (s < 257) vt2[((size_t)(bh*64 + d))*288 + s] = t[cc+j][d];
    }
  }
}

// x (f32 or bf16) -> f32 residual stream
__global__ __launch_bounds__(256) void cvt_f32(const void* __restrict__ in, float* __restrict__ out,
                                               const int* __restrict__ flag)
{
  const int fl = flag[0];
  size_t i = ((size_t)blockIdx.x*256 + threadIdx.x)*4;
  f32x4 o;
  if (fl){
    us4 v = *(const us4*)&((const UST*)in)[i];
#pragma unroll
    for (int j=0;j<4;j++) o[j] = b2f(v[j]);
  } else {
    o = *(const f32x4*)&((const float*)in)[i];
  }
  *(f32x4*)&out[i] = o;
}

// enc -> enc_c (bf16) AND passthrough to out (exact, dtype per flag)
__global__ __launch_bounds__(256) void encpass(const void* __restrict__ in, UST* __restrict__ enc_c,
                                               void* __restrict__ outp, const int* __restrict__ flag)
{
  const int fl = flag[0];
  size_t i = ((size_t)blockIdx.x*256 + threadIdx.x)*4;
  if (fl){
    us4 v = *(const us4*)&((const UST*)in)[i];
    *(us4*)&enc_c[i] = v;
    *(us4*)&((UST*)outp)[8388608 + i] = v;
  } else {
    f32x4 v = *(const f32x4*)&((const float*)in)[i];
    us4 c;
#pragma unroll
    for (int j=0;j<4;j++) c[j] = f2b(v[j]);
    *(us4*)&enc_c[i] = c;
    *(f32x4*)&((float*)outp)[8388608 + i] = v;
  }
}

extern "C" void kernel_launch(void* const* d_in, const int* in_sizes, int n_in,
                              void* d_out, int out_size, void* d_ws, size_t ws_size,
                              hipStream_t stream) {
  (void)in_sizes; (void)n_in; (void)out_size; (void)ws_size;
  const void* x       = d_in[0];
  const void* enc     = d_in[1];
  const void* ln1g    = d_in[2];
  const void* ln1b    = d_in[3];
  const void* ln2g    = d_in[4];
  const void* ln2b    = d_in[5];
  const void* ln3g    = d_in[6];
  const void* ln3b    = d_in[7];
  const void* qkvW    = d_in[8];
  const void* qkvB    = d_in[9];
  const void* projW   = d_in[10];
  const void* projB   = d_in[11];
  const void* caqW    = d_in[12];
  const void* caqB    = d_in[13];
  const void* cakW    = d_in[14];
  const void* cakB    = d_in[15];
  const void* cavW    = d_in[16];
  const void* cavB    = d_in[17];
  const void* caprojW = d_in[18];
  const void* caprojB = d_in[19];
  const void* fcW     = d_in[20];
  const void* fcB     = d_in[21];
  const void* mlpW    = d_in[22];
  const void* mlpB    = d_in[23];
  const void* adwW    = d_in[24];
  const void* adwB    = d_in[25];
  const void* aupW    = d_in[26];
  const void* aupB    = d_in[27];

  unsigned char* ws = (unsigned char*)d_ws;
  int*   flag = (int*)ws;                            // 256 B
  float* xf   = (float*)(ws + 256);                  // 33,554,432 B
  UST*   big  = (UST*)(ws + 33554688);               // 67,108,864 B
  UST*   h    = (UST*)(ws + 100663552);              // 16,777,216 B
  UST*   o    = (UST*)(ws + 117440768);              // 16,777,216 B
  UST*   wT   = (UST*)(ws + 134217984);              // 34,603,008 B
  UST*   encc = (UST*)(ws + 168820992);              //  4,210,688 B  (total ~173 MB)
  UST* qkvT    = wT;
  UST* projT   = wT + 3145728;
  UST* caqT    = wT + 4194304;
  UST* cakT    = wT + 5242880;
  UST* cavT    = wT + 6291456;
  UST* caprojT = wT + 7340032;
  UST* fcT     = wT + 8388608;
  UST* mlpT    = wT + 12582912;
  UST* adwT    = wT + 16777216;
  UST* aupT    = wT + 17039360;
  // inside big:
  UST* q2  = big;                 // 16.8 MB
  UST* k2  = big + 8388608;       //  4.2 MB
  UST* v2  = big + 10493952;      //  4.2 MB
  UST* vtX = big + 25165824;      // 16 MB (V^T scratch)

  detect_k<<<1,256,0,stream>>>((const unsigned int*)x, flag);

  // --- weight transposes ([K][N] -> [N][K] bf16) ---
  transposeW<<<dim3(48,16),256,0,stream>>>(qkvW,    qkvT,    1024, 3072, flag);
  transposeW<<<dim3(16,16),256,0,stream>>>(projW,   projT,   1024, 1024, flag);
  transposeW<<<dim3(16,16),256,0,stream>>>(caqW,    caqT,    1024, 1024, flag);
  transposeW<<<dim3(16,16),256,0,stream>>>(cakW,    cakT,    1024, 1024, flag);
  transposeW<<<dim3(16,16),256,0,stream>>>(cavW,    cavT,    1024, 1024, flag);
  transposeW<<<dim3(16,16),256,0,stream>>>(caprojW, caprojT, 1024, 1024, flag);
  transposeW<<<dim3(64,16),256,0,stream>>>(fcW,     fcT,     1024, 4096, flag);
  transposeW<<<dim3(16,64),256,0,stream>>>(mlpW,    mlpT,    4096, 1024, flag);
  transposeW<<<dim3(4,16), 256,0,stream>>>(adwW,    adwT,    1024, 256,  flag);
  transposeW<<<dim3(16,4), 256,0,stream>>>(aupW,    aupT,    256,  1024, flag);

  // --- residual stream f32; enc passthrough + bf16 copy ---
  cvt_f32<<<8192,256,0,stream>>>(x, xf, flag);
  encpass<<<2056,256,0,stream>>>(enc, encc, d_out, flag);

  // --- self attention ---
  ln_k<<<8192,256,0,stream>>>(xf, ln1g, ln1b, h, flag);
  gemm128<0,false><<<dim3(24,64),256,0,stream>>>(h, qkvT, qkvB, 8192, 3072, 1024, big, nullptr, nullptr, flag);
  transposeVself<<<dim3(16,128),256,0,stream>>>(big, vtX);
  attn2<true><<<dim3(8,128),256,0,stream>>>(big, (size_t)1024*3072, 3072,
                                            big+1024, (size_t)1024*3072, 3072,
                                            vtX, 1024, o, 1024);
  gemm128<3,false><<<dim3(8,64),256,0,stream>>>(o, projT, projB, 8192, 1024, 1024, nullptr, xf, nullptr, flag);

  // --- cross attention ---
  ln_k<<<8192,256,0,stream>>>(xf, ln3g, ln3b, h, flag);
  gemm128<0,false><<<dim3(8,64),256,0,stream>>>(h, caqT, caqB, 8192, 1024, 1024, q2, nullptr, nullptr, flag);
  gemm128<0,true ><<<dim3(8,17),256,0,stream>>>(encc, cakT, cakB, 2056, 1024, 1024, k2, nullptr, nullptr, flag);
  gemm128<0,true ><<<dim3(8,17),256,0,stream>>>(encc, cavT, cavB, 2056, 1024, 1024, v2, nullptr, nullptr, flag);
  transposeVcross<<<dim3(5,128),256,0,stream>>>(v2, vtX);
  attn2<false><<<dim3(16,128),256,0,stream>>>(q2, (size_t)1024*1024, 1024,
                                              k2, (size_t)257*1024, 1024,
                                              vtX, 288, o, 257);
  gemm128<3,false><<<dim3(8,64),256,0,stream>>>(o, caprojT, caprojB, 8192, 1024, 1024, nullptr, xf, nullptr, flag);

  // --- MLP ---
  ln_k<<<8192,256,0,stream>>>(xf, ln2g, ln2b, h, flag);
  gemm128<1,false><<<dim3(32,64),256,0,stream>>>(h, fcT, fcB, 8192, 4096, 1024, big, nullptr, nullptr, flag);
  gemm128<4,false><<<dim3(8,64),256,0,stream>>>(big, mlpT, mlpB, 8192, 1024, 4096, nullptr, xf, h, flag);

  // --- adapter ---
  gemm128<2,false><<<dim3(2,64),256,0,stream>>>(h, adwT, adwB, 8192, 256, 1024, o, nullptr, nullptr, flag);
  gemm128<5,false><<<dim3(8,64),256,0,stream>>>(o, aupT, aupB, 8192, 1024, 256, nullptr, xf, d_out, flag);
}

// Round 5
// 902.862 us; speedup vs baseline: 1.2180x; 1.0305x over previous
//
#include <hip/hip_runtime.h>

typedef unsigned short UST;
typedef __attribute__((ext_vector_type(8))) short short8;
typedef __attribute__((ext_vector_type(4))) float f32x4;
typedef __attribute__((ext_vector_type(4))) unsigned short us4;

#define DEV __device__ __forceinline__

DEV float b2f(UST u){ union{unsigned int i; float f;} x; x.i=((unsigned int)u)<<16; return x.f; }
DEV UST f2b(float f){ union{float f; unsigned int i;} x; x.f=f; return (UST)((x.i + 0x7FFFu + ((x.i>>16)&1u))>>16); }
// flag: 1 = inputs are bf16, 0 = inputs are f32
DEV float ldf(const void* p, size_t i, int fl){ return fl ? b2f(((const UST*)p)[i]) : ((const float*)p)[i]; }

DEV void g2l16(const UST* g, UST* l){
  __builtin_amdgcn_global_load_lds((const __attribute__((address_space(1))) unsigned int*)g,
                                   (__attribute__((address_space(3))) unsigned int*)l, 16, 0, 0);
}

// ---------------- dtype detection ----------------
__global__ __launch_bounds__(256) void detect_k(const unsigned int* __restrict__ x, int* __restrict__ flag)
{
  int tid = threadIdx.x;
  int cnt = 0;
#pragma unroll
  for (int j=0;j<4;j++){
    unsigned e = (x[tid*4+j] >> 7) & 0xFF;
    cnt += (e >= 100 && e <= 140) ? 1 : 0;
  }
  __shared__ int tot;
  if (tid==0) tot = 0;
  __syncthreads();
  atomicAdd(&tot, cnt);
  __syncthreads();
  if (tid==0) flag[0] = (tot > 512) ? 1 : 0;
}

// ---------------- GEMM v2: 1D grid + XCD-chunk swizzle + 2-phase dbuf ----------------
// C[M,N] = A[M,K] @ Bt[N,K]^T + bias
// grid: nwg = (N/128)*(gy) blocks, gy = ceil(M/128). bx = N-tile (XCD-chunk-major), by = M-tile (fast).
// EPI: 0 store bf16; 1 gelu->bf16; 2 relu->bf16; 3 resid+=; 4 resid+= & aux=bf16(resid); 5 out=resid+acc (dtype per flag)
template<int EPI, bool MTAIL>
__global__ __launch_bounds__(256) void gemm128(
    const UST* __restrict__ A, const UST* __restrict__ Bt, const void* __restrict__ bias,
    int M, int N, int K, int gy,
    UST* __restrict__ out, float* __restrict__ resid, void* __restrict__ aux,
    const int* __restrict__ flag)
{
  __shared__ UST As[2][128*32];
  __shared__ UST Bs[2][128*32];
  const int fl = flag[0];
  int tid = threadIdx.x;

  // XCD-chunked bijective swizzle (nwg % 8 == 0 for all our launches)
  int nwg = gridDim.x;
  int cpx = nwg >> 3;
  int o = (blockIdx.x & 7)*cpx + (blockIdx.x >> 3);
  int bx = o / gy, by = o % gy;

  int lane = tid & 63, w = tid >> 6;
  int wr = w >> 1, wc = w & 1;
  int lr = lane & 15, lk = (lane >> 4) << 3;

  // stage geometry: chunk c (0..511) = row (c>>2), k-chunk (c&3)*8
  int c0 = tid, c1 = tid + 256;
  int ar0 = by*128 + (c0>>2), ar1 = by*128 + (c1>>2);
  if (MTAIL){ ar0 = ar0 < M ? ar0 : M-1; ar1 = ar1 < M ? ar1 : M-1; }
  int br0 = bx*128 + (c0>>2), br1 = bx*128 + (c1>>2);
  int ak0 = (c0&3)<<3, ak1 = (c1&3)<<3;
  const UST* pa0 = A + (size_t)ar0*K + ak0;
  const UST* pa1 = A + (size_t)ar1*K + ak1;
  const UST* pb0 = Bt + (size_t)br0*K + ak0;
  const UST* pb1 = Bt + (size_t)br1*K + ak1;

  f32x4 acc[4][4] = {};

  int nt = K >> 5;
  // prologue: stage tile 0 into buf 0
  g2l16(pa0, &As[0][c0*8]); g2l16(pa1, &As[0][c1*8]);
  g2l16(pb0, &Bs[0][c0*8]); g2l16(pb1, &Bs[0][c1*8]);
  __syncthreads();

  int cur = 0;
  for (int t = 0; t < nt; t++){
    int nxt = cur ^ 1;
    if (t+1 < nt){
      int ko = (t+1) << 5;
      g2l16(pa0 + ko, &As[nxt][c0*8]); g2l16(pa1 + ko, &As[nxt][c1*8]);
      g2l16(pb0 + ko, &Bs[nxt][c0*8]); g2l16(pb1 + ko, &Bs[nxt][c1*8]);
    }
    short8 af[4], bf[4];
#pragma unroll
    for (int m=0;m<4;m++) af[m] = *(const short8*)&As[cur][(wr*64 + m*16 + lr)*32 + lk];
#pragma unroll
    for (int n=0;n<4;n++) bf[n] = *(const short8*)&Bs[cur][(wc*64 + n*16 + lr)*32 + lk];
    __builtin_amdgcn_s_setprio(1);
#pragma unroll
    for (int m=0;m<4;m++)
#pragma unroll
      for (int n=0;n<4;n++)
        acc[m][n] = __builtin_amdgcn_mfma_f32_16x16x32_bf16(af[m], bf[n], acc[m][n], 0,0,0);
    __builtin_amdgcn_s_setprio(0);
    __syncthreads();   // drains next-tile staging (vmcnt) after compute overlapped with it
    cur = nxt;
  }

  float bv[4];
#pragma unroll
  for (int n=0;n<4;n++) bv[n] = ldf(bias, bx*128 + wc*64 + n*16 + lr, fl);
#pragma unroll
  for (int m=0;m<4;m++){
#pragma unroll
    for (int r=0;r<4;r++){
      int gr = by*128 + wr*64 + m*16 + ((lane>>4)<<2) + r;
      if (MTAIL && gr >= M) continue;
#pragma unroll
      for (int n=0;n<4;n++){
        int gc = bx*128 + wc*64 + n*16 + lr;
        float v = acc[m][n][r] + bv[n];
        size_t idx = (size_t)gr*N + gc;
        if (EPI == 0){ out[idx] = f2b(v); }
        else if (EPI == 1){ float e = __expf(-1.5957691216f*(v + 0.044715f*v*v*v)); out[idx] = f2b(v/(1.f+e)); }
        else if (EPI == 2){ out[idx] = f2b(v > 0.f ? v : 0.f); }
        else if (EPI == 3){ resid[idx] += v; }
        else if (EPI == 4){ float x2 = resid[idx] + v; resid[idx] = x2; ((UST*)aux)[idx] = f2b(x2); }
        else { float x2 = resid[idx] + v; if (fl) ((UST*)aux)[idx] = f2b(x2); else ((float*)aux)[idx] = x2; }
      }
    }
  }
}

// ---------------- LayerNorm: f32 row -> bf16 ----------------
__global__ __launch_bounds__(256) void ln_k(const float* __restrict__ xf, const void* __restrict__ g,
                                            const void* __restrict__ b, UST* __restrict__ out,
                                            const int* __restrict__ flag)
{
  const int fl = flag[0];
  int row = blockIdx.x, tid = threadIdx.x;
  const float* xr = xf + (size_t)row*1024;
  f32x4 v = *(const f32x4*)&xr[tid*4];
  float s = v[0]+v[1]+v[2]+v[3];
  float ss = v[0]*v[0]+v[1]*v[1]+v[2]*v[2]+v[3]*v[3];
#pragma unroll
  for (int off=32; off>0; off>>=1){ s += __shfl_down(s, off); ss += __shfl_down(ss, off); }
  __shared__ float sm[8];
  int w = tid>>6;
  if ((tid&63)==0){ sm[w] = s; sm[4+w] = ss; }
  __syncthreads();
  s = sm[0]+sm[1]+sm[2]+sm[3];
  ss = sm[4]+sm[5]+sm[6]+sm[7];
  float mu = s*(1.f/1024.f);
  float rs = rsqrtf(ss*(1.f/1024.f) - mu*mu + 1e-5f);
  us4 o;
#pragma unroll
  for (int j=0;j<4;j++){
    int c = tid*4+j;
    o[j] = f2b((v[j]-mu)*rs*ldf(g,c,fl) + ldf(b,c,fl));
  }
  *(us4*)&out[(size_t)row*1024 + tid*4] = o;
}

// ---------------- flash attention v2: LDS-staged K/V, KVBLK=64, 2-phase dbuf ----------------
// CAUSAL => paired q-tiles {15-p, p} per block (balanced 17 KV-tiles/block).
#define NEGBIG (-1e30f)
template<bool CAUSAL>
__global__ __launch_bounds__(256) void attn2(
    const UST* __restrict__ Qb, size_t qB, int qT,
    const UST* __restrict__ Kb, size_t kB, int kT,
    const UST* __restrict__ Vt, int vS,
    UST* __restrict__ O, int nk)
{
  __shared__ UST Ks[2][4096];            // [2][64 keys][64 d], XOR-swizzled rows (128B)
  __shared__ UST Vs[2][4096];            // [2][64 d][64 keys], XOR-swizzled rows (128B)
  __shared__ UST plds[4][16][72];        // per-wave P tile, padded rows (144B, 16B-aligned)

  int p = blockIdx.x, bh = blockIdx.y;
  int b = bh >> 4, h = bh & 15;
  int tid = threadIdx.x, w = tid >> 6, lane = tid & 63;
  int lr = lane & 15;
  const UST* q0 = Qb + (size_t)b*qB + h*64;
  const UST* kp = Kb + (size_t)b*kB + h*64;
  const UST* vp = Vt + (size_t)bh*64*vS;
  const int skmax = nk - 1;

  auto stageK = [&](int bufi, int s0){
#pragma unroll
    for (int it=0; it<2; it++){
      int c = tid + it*256;
      int s = c >> 3;
      int srcb = ((c & 7) << 4) ^ ((s & 7) << 4);
      int sg = s0 + s; sg = sg <= skmax ? sg : skmax;
      g2l16(kp + (size_t)sg*kT + (srcb>>1), &Ks[bufi][c*8]);
    }
  };
  auto stageV = [&](int bufi, int s0){
#pragma unroll
    for (int it=0; it<2; it++){
      int c = tid + it*256;
      int d = c >> 3;
      int srcb = ((c & 7) << 4) ^ ((d & 7) << 4);
      g2l16(vp + (size_t)d*vS + s0 + (srcb>>1), &Vs[bufi][c*8]);
    }
  };

  int qtiles[2]; int nq;
  if (CAUSAL){ qtiles[0] = 15 - p; qtiles[1] = p; nq = 2; }
  else       { qtiles[0] = p; nq = 1; }

  for (int qi=0; qi<nq; qi++){
    int qt = qtiles[qi];
    int t0 = qt*64 + w*16;
    int qr0 = t0 + ((lane>>4)<<2);
    short8 qf0 = *(const short8*)&q0[(size_t)(t0+lr)*qT + ((lane>>4)<<3)];
    short8 qf1 = *(const short8*)&q0[(size_t)(t0+lr)*qT + 32 + ((lane>>4)<<3)];
    f32x4 oacc[4] = {};
    float m[4], l[4];
#pragma unroll
    for (int r=0;r<4;r++){ m[r] = NEGBIG; l[r] = 0.f; }

    int nt = CAUSAL ? (qt + 1) : ((nk + 63) >> 6);
    int cur = 0;
    stageK(0, 0); stageV(0, 0);
    __syncthreads();

    for (int t=0; t<nt; t++){
      int s0 = t*64;
      int nxt = cur ^ 1;
      if (t+1 < nt){ stageK(nxt, s0 + 64); stageV(nxt, s0 + 64); }

      // ---- QK^T: 64 keys ----
      f32x4 sf[4];
      const char* ksb = (const char*)&Ks[cur][0];
      __builtin_amdgcn_s_setprio(1);
#pragma unroll
      for (int hf=0; hf<4; hf++){
        int r = hf*16 + lr;
        int sw = (r & 7) << 4;
        int lo = (lane >> 4) << 4;
        short8 k0 = *(const short8*)(ksb + r*128 + (lo ^ sw));
        short8 k1 = *(const short8*)(ksb + r*128 + ((64 + lo) ^ sw));
        f32x4 s_ = {};
        s_ = __builtin_amdgcn_mfma_f32_16x16x32_bf16(qf0, k0, s_, 0,0,0);
        s_ = __builtin_amdgcn_mfma_f32_16x16x32_bf16(qf1, k1, s_, 0,0,0);
        sf[hf] = s_;
      }
      __builtin_amdgcn_s_setprio(0);

      bool needMask = (CAUSAL && (s0+63 > t0)) || (s0+63 >= nk);
#pragma unroll
      for (int hf=0; hf<4; hf++)
#pragma unroll
        for (int r=0;r<4;r++){
          float sv = sf[hf][r]*0.125f;
          if (needMask){
            int key = s0 + hf*16 + lr;
            if ((CAUSAL && key > qr0 + r) || key >= nk) sv = NEGBIG;
          }
          sf[hf][r] = sv;
        }

      float mx[4];
#pragma unroll
      for (int r=0;r<4;r++) mx[r] = fmaxf(fmaxf(sf[0][r], sf[1][r]), fmaxf(sf[2][r], sf[3][r]));
#pragma unroll
      for (int off=1; off<16; off<<=1)
#pragma unroll
        for (int r=0;r<4;r++) mx[r] = fmaxf(mx[r], __shfl_xor(mx[r], off));
      float scl[4];
#pragma unroll
      for (int r=0;r<4;r++){
        float mn = fmaxf(m[r], mx[r]);
        scl[r] = __expf(m[r] - mn);
        m[r] = mn;
      }
#pragma unroll
      for (int hf=0; hf<4; hf++)
#pragma unroll
        for (int r=0;r<4;r++){
          float d = sf[hf][r] - m[r];
          sf[hf][r] = (d < -80.f) ? 0.f : __expf(d);
        }
      float sum[4];
#pragma unroll
      for (int r=0;r<4;r++) sum[r] = (sf[0][r] + sf[1][r]) + (sf[2][r] + sf[3][r]);
#pragma unroll
      for (int off=1; off<16; off<<=1)
#pragma unroll
        for (int r=0;r<4;r++) sum[r] += __shfl_xor(sum[r], off);
#pragma unroll
      for (int r=0;r<4;r++) l[r] = l[r]*scl[r] + sum[r];
#pragma unroll
      for (int nf=0;nf<4;nf++)
#pragma unroll
        for (int r=0;r<4;r++) oacc[nf][r] *= scl[r];

      // ---- P -> LDS (per-wave) ----
#pragma unroll
      for (int hf=0; hf<4; hf++)
#pragma unroll
        for (int r=0;r<4;r++)
          plds[w][((lane>>4)<<2)+r][hf*16+lr] = f2b(sf[hf][r]);

      const char* pb = (const char*)&plds[w][0][0];
      short8 pf0 = *(const short8*)(pb + lr*144 +      ((lane>>4)<<4));
      short8 pf1 = *(const short8*)(pb + lr*144 + 64 + ((lane>>4)<<4));

      // ---- PV: oacc += P @ V^T ----
      const char* vsb = (const char*)&Vs[cur][0];
      __builtin_amdgcn_s_setprio(1);
#pragma unroll
      for (int nf=0; nf<4; nf++){
        int d = nf*16 + lr;
        int sw = (d & 7) << 4;
        int lo = (lane >> 4) << 4;
        short8 vf0 = *(const short8*)(vsb + d*128 + (lo ^ sw));
        short8 vf1 = *(const short8*)(vsb + d*128 + ((64 + lo) ^ sw));
        oacc[nf] = __builtin_amdgcn_mfma_f32_16x16x32_bf16(pf0, vf0, oacc[nf], 0,0,0);
        oacc[nf] = __builtin_amdgcn_mfma_f32_16x16x32_bf16(pf1, vf1, oacc[nf], 0,0,0);
      }
      __builtin_amdgcn_s_setprio(0);

      __syncthreads();
      cur = nxt;
    }

#pragma unroll
    for (int nf=0;nf<4;nf++)
#pragma unroll
      for (int r=0;r<4;r++){
        int t = t0 + ((lane>>4)<<2) + r;
        O[(size_t)(b*1024 + t)*1024 + h*64 + nf*16 + lr] = f2b(oacc[nf][r] / l[r]);
      }
  }
}

// ---------------- weight transpose: in[K][N] (f32 or bf16) -> out[N][K] bf16 ----------------
__global__ __launch_bounds__(256) void transposeW(const void* __restrict__ in, UST* __restrict__ out,
                                                  int K, int N, const int* __restrict__ flag)
{
  const int fl = flag[0];
  int n0 = blockIdx.x*64, k0 = blockIdx.y*64;
  __shared__ UST t[64][72];
  int tid = threadIdx.x;
  int r = tid>>3, cc = (tid&7)*8;
#pragma unroll
  for (int it=0; it<2; it++){
    int k = r + it*32;
    short8 v;
    if (fl){
      v = *(const short8*)&((const UST*)in)[(size_t)(k0+k)*N + n0 + cc];
    } else {
      const float* inf = (const float*)in;
      f32x4 a = *(const f32x4*)&inf[(size_t)(k0+k)*N + n0 + cc];
      f32x4 b = *(const f32x4*)&inf[(size_t)(k0+k)*N + n0 + cc + 4];
#pragma unroll
      for (int j=0;j<4;j++){ v[j] = (short)f2b(a[j]); v[4+j] = (short)f2b(b[j]); }
    }
    *(short8*)&t[k][cc] = v;
  }
  __syncthreads();
#pragma unroll
  for (int it=0; it<2; it++){
    int n = r + it*32;
    short8 v;
#pragma unroll
    for (int j=0;j<8;j++) v[j] = t[cc+j][n];
    *(short8*)&out[(size_t)(n0+n)*K + k0 + cc] = v;
  }
}

// V (self) from qkv[8192][3072] cols 2048+.. -> vt[bh*64+d][1024]
__global__ __launch_bounds__(256) void transposeVself(const UST* __restrict__ qkv, UST* __restrict__ vt)
{
  int t0 = blockIdx.x*64; int bh = blockIdx.y; int b = bh>>4, h = bh&15;
  __shared__ UST t[64][72];
  int tid = threadIdx.x, r = tid>>3, cc = (tid&7)*8;
#pragma unroll
  for (int it=0; it<2; it++){
    int tt = r + it*32;
    short8 v = *(const short8*)&qkv[((size_t)(b*1024 + t0 + tt))*3072 + 2048 + h*64 + cc];
    *(short8*)&t[tt][cc] = v;
  }
  __syncthreads();
#pragma unroll
  for (int it=0; it<2; it++){
    int d = r + it*32;
    short8 v;
#pragma unroll
    for (int j=0;j<8;j++) v[j] = t[cc+j][d];
    *(short8*)&vt[((size_t)(bh*64 + d))*1024 + t0 + cc] = v;
  }
}

// V (cross) from v2[2056][1024] -> vt2[bh*64+d][288] (s<257 valid)
__global__ __launch_bounds__(256) void transposeVcross(const UST* __restrict__ v2, UST* __restrict__ vt2)
{
  int s0 = blockIdx.x*64; int bh = blockIdx.y; int b = bh>>4, h = bh&15;
  __shared__ UST t[64][72];
  int tid = threadIdx.x, r = tid>>3, cc = (tid&7)*8;
#pragma unroll
  for (int it=0; it<2; it++){
    int s = s0 + r + it*32; if (s > 256) s = 256;
    short8 v = *(const short8*)&v2[((size_t)(b*257 + s))*1024 + h*64 + cc];
    *(short8*)&t[r+it*32][cc] = v;
  }
  __syncthreads();
#pragma unroll
  for (int it=0; it<2; it++){
    int d = r + it*32;
#pragma unroll
    for (int j=0;j<8;j++){
      int s = s0 + cc + j;
      if (s < 257) vt2[((size_t)(bh*64 + d))*288 + s] = t[cc+j][d];
    }
  }
}

// x (f32 or bf16) -> f32 residual stream
__global__ __launch_bounds__(256) void cvt_f32(const void* __restrict__ in, float* __restrict__ out,
                                               const int* __restrict__ flag)
{
  const int fl = flag[0];
  size_t i = ((size_t)blockIdx.x*256 + threadIdx.x)*4;
  f32x4 o;
  if (fl){
    us4 v = *(const us4*)&((const UST*)in)[i];
#pragma unroll
    for (int j=0;j<4;j++) o[j] = b2f(v[j]);
  } else {
    o = *(const f32x4*)&((const float*)in)[i];
  }
  *(f32x4*)&out[i] = o;
}

// enc -> enc_c (bf16) AND passthrough to out (exact, dtype per flag)
__global__ __launch_bounds__(256) void encpass(const void* __restrict__ in, UST* __restrict__ enc_c,
                                               void* __restrict__ outp, const int* __restrict__ flag)
{
  const int fl = flag[0];
  size_t i = ((size_t)blockIdx.x*256 + threadIdx.x)*4;
  if (fl){
    us4 v = *(const us4*)&((const UST*)in)[i];
    *(us4*)&enc_c[i] = v;
    *(us4*)&((UST*)outp)[8388608 + i] = v;
  } else {
    f32x4 v = *(const f32x4*)&((const float*)in)[i];
    us4 c;
#pragma unroll
    for (int j=0;j<4;j++) c[j] = f2b(v[j]);
    *(us4*)&enc_c[i] = c;
    *(f32x4*)&((float*)outp)[8388608 + i] = v;
  }
}

extern "C" void kernel_launch(void* const* d_in, const int* in_sizes, int n_in,
                              void* d_out, int out_size, void* d_ws, size_t ws_size,
                              hipStream_t stream) {
  (void)in_sizes; (void)n_in; (void)out_size; (void)ws_size;
  const void* x       = d_in[0];
  const void* enc     = d_in[1];
  const void* ln1g    = d_in[2];
  const void* ln1b    = d_in[3];
  const void* ln2g    = d_in[4];
  const void* ln2b    = d_in[5];
  const void* ln3g    = d_in[6];
  const void* ln3b    = d_in[7];
  const void* qkvW    = d_in[8];
  const void* qkvB    = d_in[9];
  const void* projW   = d_in[10];
  const void* projB   = d_in[11];
  const void* caqW    = d_in[12];
  const void* caqB    = d_in[13];
  const void* cakW    = d_in[14];
  const void* cakB    = d_in[15];
  const void* cavW    = d_in[16];
  const void* cavB    = d_in[17];
  const void* caprojW = d_in[18];
  const void* caprojB = d_in[19];
  const void* fcW     = d_in[20];
  const void* fcB     = d_in[21];
  const void* mlpW    = d_in[22];
  const void* mlpB    = d_in[23];
  const void* adwW    = d_in[24];
  const void* adwB    = d_in[25];
  const void* aupW    = d_in[26];
  const void* aupB    = d_in[27];

  unsigned char* ws = (unsigned char*)d_ws;
  int*   flag = (int*)ws;                            // 256 B
  float* xf   = (float*)(ws + 256);                  // 33,554,432 B
  UST*   big  = (UST*)(ws + 33554688);               // 67,108,864 B
  UST*   h    = (UST*)(ws + 100663552);              // 16,777,216 B
  UST*   o    = (UST*)(ws + 117440768);              // 16,777,216 B
  UST*   wT   = (UST*)(ws + 134217984);              // 34,603,008 B
  UST*   encc = (UST*)(ws + 168820992);              //  4,210,688 B  (total ~173 MB)
  UST* qkvT    = wT;
  UST* projT   = wT + 3145728;
  UST* caqT    = wT + 4194304;
  UST* cakT    = wT + 5242880;
  UST* cavT    = wT + 6291456;
  UST* caprojT = wT + 7340032;
  UST* fcT     = wT + 8388608;
  UST* mlpT    = wT + 12582912;
  UST* adwT    = wT + 16777216;
  UST* aupT    = wT + 17039360;
  // inside big:
  UST* q2  = big;                 // 16.8 MB
  UST* k2  = big + 8388608;       //  4.2 MB
  UST* v2  = big + 10493952;      //  4.2 MB
  UST* vtX = big + 25165824;      // 16 MB (V^T scratch)

  detect_k<<<1,256,0,stream>>>((const unsigned int*)x, flag);

  // --- weight transposes ([K][N] -> [N][K] bf16) ---
  transposeW<<<dim3(48,16),256,0,stream>>>(qkvW,    qkvT,    1024, 3072, flag);
  transposeW<<<dim3(16,16),256,0,stream>>>(projW,   projT,   1024, 1024, flag);
  transposeW<<<dim3(16,16),256,0,stream>>>(caqW,    caqT,    1024, 1024, flag);
  transposeW<<<dim3(16,16),256,0,stream>>>(cakW,    cakT,    1024, 1024, flag);
  transposeW<<<dim3(16,16),256,0,stream>>>(cavW,    cavT,    1024, 1024, flag);
  transposeW<<<dim3(16,16),256,0,stream>>>(caprojW, caprojT, 1024, 1024, flag);
  transposeW<<<dim3(64,16),256,0,stream>>>(fcW,     fcT,     1024, 4096, flag);
  transposeW<<<dim3(16,64),256,0,stream>>>(mlpW,    mlpT,    4096, 1024, flag);
  transposeW<<<dim3(4,16), 256,0,stream>>>(adwW,    adwT,    1024, 256,  flag);
  transposeW<<<dim3(16,4), 256,0,stream>>>(aupW,    aupT,    256,  1024, flag);

  // --- residual stream f32; enc passthrough + bf16 copy ---
  cvt_f32<<<8192,256,0,stream>>>(x, xf, flag);
  encpass<<<2056,256,0,stream>>>(enc, encc, d_out, flag);

  // --- self attention ---
  ln_k<<<8192,256,0,stream>>>(xf, ln1g, ln1b, h, flag);
  gemm128<0,false><<<24*64,256,0,stream>>>(h, qkvT, qkvB, 8192, 3072, 1024, 64, big, nullptr, nullptr, flag);
  transposeVself<<<dim3(16,128),256,0,stream>>>(big, vtX);
  attn2<true><<<dim3(8,128),256,0,stream>>>(big, (size_t)1024*3072, 3072,
                                            big+1024, (size_t)1024*3072, 3072,
                                            vtX, 1024, o, 1024);
  gemm128<3,false><<<8*64,256,0,stream>>>(o, projT, projB, 8192, 1024, 1024, 64, nullptr, xf, nullptr, flag);

  // --- cross attention ---
  ln_k<<<8192,256,0,stream>>>(xf, ln3g, ln3b, h, flag);
  gemm128<0,false><<<8*64,256,0,stream>>>(h, caqT, caqB, 8192, 1024, 1024, 64, q2, nullptr, nullptr, flag);
  gemm128<0,true ><<<8*17,256,0,stream>>>(encc, cakT, cakB, 2056, 1024, 1024, 17, k2, nullptr, nullptr, flag);
  gemm128<0,true ><<<8*17,256,0,stream>>>(encc, cavT, cavB, 2056, 1024, 1024, 17, v2, nullptr, nullptr, flag);
  transposeVcross<<<dim3(5,128),256,0,stream>>>(v2, vtX);
  attn2<false><<<dim3(16,128),256,0,stream>>>(q2, (size_t)1024*1024, 1024,
                                              k2, (size_t)257*1024, 1024,
                                              vtX, 288, o, 257);
  gemm128<3,false><<<8*64,256,0,stream>>>(o, caprojT, caprojB, 8192, 1024, 1024, 64, nullptr, xf, nullptr, flag);

  // --- MLP ---
  ln_k<<<8192,256,0,stream>>>(xf, ln2g, ln2b, h, flag);
  gemm128<1,false><<<32*64,256,0,stream>>>(h, fcT, fcB, 8192, 4096, 1024, 64, big, nullptr, nullptr, flag);
  gemm128<4,false><<<8*64,256,0,stream>>>(big, mlpT, mlpB, 8192, 1024, 4096, 64, nullptr, xf, h, flag);

  // --- adapter ---
  gemm128<2,false><<<2*64,256,0,stream>>>(h, adwT, adwB, 8192, 256, 1024, 64, o, nullptr, nullptr, flag);
  gemm128<5,false><<<8*64,256,0,stream>>>(o, aupT, aupB, 8192, 1024, 256, 64, nullptr, xf, d_out, flag);
}